// Round 11
// baseline (141.677 us; speedup 1.0000x reference)
//
#include <hip/hip_runtime.h>
#include <cmath>

// ---------------------------------------------------------------------------
// Problem constants (from reference)
// ---------------------------------------------------------------------------
constexpr int kNsh    = 9;      // (LMAX+1)^2, LMAX=2
constexpr int kF      = 64;
constexpr int kNrbf   = 20;
constexpr int kNAtoms = 1000;
constexpr int kNPairs = 10000;
constexpr float kCutoffF = 5.0f;
constexpr int kMaxNZ  = 200;
constexpr int kCp     = 12;         // channel dim padded (9 -> 12) for b128
constexpr int kXs     = kF * kCp;   // 768 floats per atom, internal layout

// ---------------------------------------------------------------------------
// Compile-time real Clebsch-Gordan table (mirrors the reference _real_cg)
// ---------------------------------------------------------------------------
struct CGSparse {
  int n;
  int c[kMaxNZ];
  int a[kMaxNZ];
  int b[kMaxNZ];
  float v[kMaxNZ];
};

constexpr double cfact(int n) {
  double r = 1.0;
  for (int i = 2; i <= n; i++) r *= (double)i;
  return r;
}
constexpr double cabs_(double x) { return x < 0 ? -x : x; }
constexpr double csqrt_(double x) {
  if (x <= 0.0) return 0.0;
  double g = x < 1.0 ? 1.0 : x;
  for (int i = 0; i < 60; i++) g = 0.5 * (g + x / g);
  return g;
}

constexpr double cg_cplx(int l1, int m1, int l2, int m2, int l3, int m3) {
  if (m3 != m1 + m2) return 0.0;
  int lo = l1 > l2 ? l1 - l2 : l2 - l1;
  if (l3 < lo || l3 > l1 + l2) return 0.0;
  double pre = csqrt_((2 * l3 + 1) * cfact(l3 + l1 - l2) * cfact(l3 - l1 + l2) *
                      cfact(l1 + l2 - l3) / cfact(l1 + l2 + l3 + 1));
  pre *= csqrt_(cfact(l3 + m3) * cfact(l3 - m3) * cfact(l1 - m1) *
                cfact(l1 + m1) * cfact(l2 - m2) * cfact(l2 + m2));
  double s = 0.0;
  for (int k = 0; k <= l1 + l2 - l3; k++) {
    int d0 = k, d1 = l1 + l2 - l3 - k, d2 = l1 - m1 - k;
    int d3 = l2 + m2 - k, d4 = l3 - l2 + m1 + k, d5 = l3 - l1 - m2 + k;
    if (d0 < 0 || d1 < 0 || d2 < 0 || d3 < 0 || d4 < 0 || d5 < 0) continue;
    double den = cfact(d0) * cfact(d1) * cfact(d2) * cfact(d3) * cfact(d4) * cfact(d5);
    s += ((k % 2) ? -1.0 : 1.0) / den;
  }
  return pre * s;
}

constexpr CGSparse build_cg() {
  CGSparse out{};
  int lidx[9] = {0, 1, 1, 1, 2, 2, 2, 2, 2};
  int midx[9] = {0, -1, 0, 1, -2, -1, 0, 1, 2};
  double Ur[9][9] = {};
  double Ui[9][9] = {};
  for (int l = 0; l <= 2; l++) {
    int base = l * l + l;
    Ur[base][base] = 1.0;
    for (int m = 1; m <= l; m++) {
      double s2 = 1.0 / csqrt_(2.0);
      double sgn = (m % 2) ? -1.0 : 1.0;
      Ur[base + m][base - m] = s2;
      Ur[base + m][base + m] = sgn * s2;
      Ui[base - m][base - m] = s2;
      Ui[base - m][base + m] = -sgn * s2;
    }
  }
  double cgr[9][9][9] = {};
  for (int i = 0; i < 9; i++)
    for (int j = 0; j < 9; j++)
      for (int k = 0; k < 9; k++) {
        double cv = cg_cplx(lidx[i], midx[i], lidx[j], midx[j], lidx[k], midx[k]);
        if (cv == 0.0) continue;
        for (int a2 = 0; a2 < 9; a2++) {
          if (Ur[a2][i] == 0.0 && Ui[a2][i] == 0.0) continue;
          for (int b2 = 0; b2 < 9; b2++) {
            if (Ur[b2][j] == 0.0 && Ui[b2][j] == 0.0) continue;
            for (int c2 = 0; c2 < 9; c2++) {
              if (Ur[c2][k] == 0.0 && Ui[c2][k] == 0.0) continue;
              double ar = Ur[a2][i], ai = Ui[a2][i];
              double br = Ur[b2][j], bi = Ui[b2][j];
              double cr = Ur[c2][k], ci = -Ui[c2][k];  // conj
              double pr = ar * br - ai * bi;
              double pi = ar * bi + ai * br;
              double rr = pr * cr - pi * ci;  // real part
              cgr[c2][a2][b2] += rr * cv;
            }
          }
        }
      }
  int n = 0;
  for (int c2 = 0; c2 < 9; c2++)
    for (int a2 = 0; a2 < 9; a2++)
      for (int b2 = 0; b2 < 9; b2++) {
        bool mask = ((lidx[a2] + lidx[b2]) % 2) == (lidx[c2] % 2);
        double v = mask ? cgr[c2][a2][b2] : 0.0;
        if (cabs_(v) > 1e-9) {
          out.c[n] = c2;
          out.a[n] = a2;
          out.b[n] = b2;
          out.v[n] = (float)v;
          n++;
        }
      }
  out.n = n;
  return out;
}

constexpr CGSparse CG = build_cg();
static_assert(CG.n > 0 && CG.n <= kMaxNZ, "CG table size out of range");

// ---------------------------------------------------------------------------
// k_pre: pair geometry + radial filters (both t) | segment offsets
// ---------------------------------------------------------------------------
constexpr int kPreBlkPairs = kNPairs / 4;                 // 2500
constexpr int kPreBlkSeg   = (kNAtoms + 1 + 255) / 256;   // 4
constexpr int kPreBlkTotal = kPreBlkPairs + kPreBlkSeg;

__global__ __launch_bounds__(256) void k_pre(
    const float* __restrict__ rij, const float* __restrict__ Wf,
    const float* __restrict__ bf, const int* __restrict__ idx_i,
    float* __restrict__ Ypd, float* __restrict__ Wpair,
    int* __restrict__ seg) {
  const int blk = blockIdx.x;
  if (blk < kPreBlkPairs) {
    int wv = threadIdx.x >> 6;
    int f = threadIdx.x & 63;
    int p = blk * 4 + wv;
    float rx = rij[3 * p + 0], ry = rij[3 * p + 1], rz = rij[3 * p + 2];
    float d = sqrtf(rx * rx + ry * ry + rz * rz);
    float inv = 1.0f / d;
    float x = rx * inv, y = ry * inv, z = rz * inv;
    const float c0 = 0.28209479177387814f;  // 0.5/sqrt(pi)
    const float c1 = 0.4886025119029199f;   // sqrt(3/(4pi))
    const float c2 = 1.0925484305920792f;   // 0.5*sqrt(15/pi)
    const float c3 = 0.31539156525252005f;  // 0.25*sqrt(5/pi)
    const float c4 = 0.5462742152960396f;   // 0.25*sqrt(15/pi)
    if (f < 9) {
      float yv =
          (f == 0) ? c0 :
          (f == 1) ? c1 * y :
          (f == 2) ? c1 * z :
          (f == 3) ? c1 * x :
          (f == 4) ? c2 * x * y :
          (f == 5) ? c2 * y * z :
          (f == 6) ? c3 * (3.0f * z * z - 1.0f) :
          (f == 7) ? c2 * x * z :
                     c4 * (x * x - y * y);
      Ypd[p * 16 + f] = yv;
    }
    float cut = (d < kCutoffF) ? 0.5f * (cosf(d * (float)(M_PI / 5.0)) + 1.0f) : 0.0f;
    float radial[kNrbf];
    const float width = kCutoffF / (kNrbf - 1);
    const float coef = -0.5f / (width * width);
    #pragma unroll
    for (int k = 0; k < kNrbf; k++) {
      float off = (kCutoffF * k) / (kNrbf - 1);
      float tt = d - off;
      radial[k] = expf(coef * tt * tt);
    }
    #pragma unroll
    for (int t = 0; t < 2; t++) {
      #pragma unroll
      for (int l = 0; l < 3; l++) {
        float w = bf[t * 192 + l * 64 + f];
        #pragma unroll
        for (int k = 0; k < kNrbf; k++) {
          w += radial[k] * Wf[t * (kNrbf * 192) + k * 192 + l * 64 + f];
        }
        Wpair[t * (kNPairs * 192) + p * 192 + l * 64 + f] = w * cut;
      }
    }
  } else {
    int a = (blk - kPreBlkPairs) * 256 + threadIdx.x;
    if (a <= kNAtoms) {
      int lo = 0, hi = kNPairs;
      while (lo < hi) {
        int mid = (lo + hi) >> 1;
        if (idx_i[mid] < a) lo = mid + 1; else hi = mid;
      }
      seg[a] = lo;
    }
  }
}

// ---------------------------------------------------------------------------
// mm64: full-K matmul, one wave, 4c x 4f register tile per lane (48 lanes
// active). sA: f-major A (sA[k*12+c]); W streamed from global (L2-broadcast).
// Result written f-major to sB.
// ---------------------------------------------------------------------------
__device__ __forceinline__ void mm64(const float* __restrict__ sA,
                                     const float* __restrict__ W,
                                     float* __restrict__ sB,
                                     int cgi, int fb) {
  if (cgi < 3) {
    const int c0 = cgi * 4;
    float acc[4][4];
    #pragma unroll
    for (int i = 0; i < 4; i++)
      #pragma unroll
      for (int j = 0; j < 4; j++) acc[i][j] = 0.f;
    #pragma unroll 8
    for (int k = 0; k < kF; k++) {
      float4 av = *(const float4*)(sA + k * kCp + c0);
      float4 wv = *(const float4*)(W + k * kF + fb);
      float a[4] = {av.x, av.y, av.z, av.w};
      float w[4] = {wv.x, wv.y, wv.z, wv.w};
      #pragma unroll
      for (int i = 0; i < 4; i++)
        #pragma unroll
        for (int j = 0; j < 4; j++) acc[i][j] += a[i] * w[j];
    }
    #pragma unroll
    for (int j = 0; j < 4; j++) {
      float4 v = {acc[0][j], acc[1][j], acc[2][j], acc[3][j]};
      *(float4*)(sB + (fb + j) * kCp + c0) = v;
    }
  }
}

// ---------------------------------------------------------------------------
// k_inter<T>: one WAVE (64-thr block) per atom; barrier-free pipeline
// (single-wave __syncthreads = cheap waitcnt). Message uses batched j-list
// prefetch + __shfl broadcast to break the per-pair dependent-load chain.
// T==0: gather emb[Z[j]] (x0 virtual), write internal [f][12].
// T==1: gather x1, write standard [c][f] to out.
// ---------------------------------------------------------------------------
template <int T>
__global__ __launch_bounds__(64) void k_inter(
    const float* __restrict__ Ypd, const float* __restrict__ Wpt,
    const int* __restrict__ seg, const int* __restrict__ idx_j,
    const int* __restrict__ Z, const float* __restrict__ emb,
    const float* __restrict__ x_in, const float* __restrict__ W1,
    const float* __restrict__ W2, const float* __restrict__ W3,
    const float* __restrict__ Wg, const float* __restrict__ bg,
    float* __restrict__ x_out) {
  const int atom = blockIdx.x;
  const int f = threadIdx.x;        // lane = feature
  const int cgi = f >> 4;           // 0..3 (3 idle in mm)
  const int fb = (f & 15) * 4;

  __shared__ __align__(16) float sA[kF * kCp + 4];  // 3 KB
  __shared__ __align__(16) float sB[kF * kCp + 4];  // 3 KB

  // ---- message: batched j prefetch + shfl broadcast ----
  float dxv[12];
  #pragma unroll
  for (int c = 0; c < 12; c++) dxv[c] = 0.f;
  {
    const int s0 = seg[atom], s1 = seg[atom + 1];
    for (int base = s0; base < s1; base += 64) {
      const int n = min(64, s1 - base);
      int jv = 0, zv = 0;
      if (f < n) jv = idx_j[base + f];
      if (T == 0) zv = (f < n) ? Z[jv] : 0;
      for (int it = 0; it < n; it++) {
        const int p = base + it;
        const float* Wp = Wpt + p * 192;
        float Wl0 = Wp[f], Wl1 = Wp[64 + f], Wl2 = Wp[128 + f];
        const float* Yp = Ypd + p * 16;
        float YW[9];
        YW[0] = Yp[0] * Wl0;
        YW[1] = Yp[1] * Wl1;
        YW[2] = Yp[2] * Wl1;
        YW[3] = Yp[3] * Wl1;
        #pragma unroll
        for (int b = 4; b < 9; b++) YW[b] = Yp[b] * Wl2;
        if (T == 0) {
          const int z = __shfl(zv, it, 64);
          float e = emb[z * kF + f];
          #pragma unroll
          for (int q = 0; q < CG.n; q++) {
            if (CG.a[q] == 0) dxv[CG.c[q]] += CG.v[q] * YW[CG.b[q]] * e;
          }
        } else {
          const int j = __shfl(jv, it, 64);
          const float* xj = x_in + j * kXs + f * kCp;
          float xv[12];
          *(float4*)&xv[0] = *(const float4*)(xj + 0);
          *(float4*)&xv[4] = *(const float4*)(xj + 4);
          *(float4*)&xv[8] = *(const float4*)(xj + 8);
          #pragma unroll
          for (int q = 0; q < CG.n; q++) {
            dxv[CG.c[q]] += CG.v[q] * YW[CG.b[q]] * xv[CG.a[q]];
          }
        }
      }
    }
  }
  // stage dx f-major
  {
    float4* sa = (float4*)(sA + f * kCp);
    sa[0] = *(float4*)&dxv[0];
    sa[1] = *(float4*)&dxv[4];
    sa[2] = *(float4*)&dxv[8];
  }
  __syncthreads();  // single-wave: waitcnt only

  // ---- matmul1: ddx = dx @ W1 -> sB ----
  mm64(sA, W1, sB, cgi, fb);
  __syncthreads();

  // ---- tp: t2 = dx + CG(dx, ddx) -> sA ----
  {
    float ddx[12];
    const float4* sb = (const float4*)(sB + f * kCp);
    *(float4*)&ddx[0] = sb[0];
    *(float4*)&ddx[4] = sb[1];
    *(float4*)&ddx[8] = sb[2];
    float t2[12];
    #pragma unroll
    for (int c = 0; c < 9; c++) t2[c] = dxv[c];
    t2[9] = 0.f; t2[10] = 0.f; t2[11] = 0.f;
    #pragma unroll
    for (int q = 0; q < CG.n; q++) {
      t2[CG.c[q]] += CG.v[q] * dxv[CG.a[q]] * ddx[CG.b[q]];
    }
    float4* sa = (float4*)(sA + f * kCp);
    sa[0] = *(float4*)&t2[0];
    sa[1] = *(float4*)&t2[4];
    sa[2] = *(float4*)&t2[8];
  }
  __syncthreads();

  // ---- matmul2: dx2 = t2 @ W2 -> sB ----
  mm64(sA, W2, sB, cgi, fb);
  __syncthreads();

  // ---- gate: g = sigmoid(dx2[0] @ Wg + bg); dx3 -> sA ----
  {
    float g0 = bg[f], g1 = bg[64 + f], g2 = bg[128 + f];
    #pragma unroll 4
    for (int k = 0; k < kF; k++) {
      float a = sB[k * kCp];          // dx2[c=0][k], broadcast
      g0 += a * Wg[k * 192 + f];
      g1 += a * Wg[k * 192 + 64 + f];
      g2 += a * Wg[k * 192 + 128 + f];
    }
    g0 = 1.f / (1.f + expf(-g0));
    g1 = 1.f / (1.f + expf(-g1));
    g2 = 1.f / (1.f + expf(-g2));
    float dx2v[12];
    const float4* sb = (const float4*)(sB + f * kCp);
    *(float4*)&dx2v[0] = sb[0];
    *(float4*)&dx2v[4] = sb[1];
    *(float4*)&dx2v[8] = sb[2];
    float dx3[12];
    dx3[0] = dx2v[0] * g0;
    dx3[1] = dx2v[1] * g1;
    dx3[2] = dx2v[2] * g1;
    dx3[3] = dx2v[3] * g1;
    #pragma unroll
    for (int c = 4; c < 9; c++) dx3[c] = dx2v[c] * g2;
    dx3[9] = 0.f; dx3[10] = 0.f; dx3[11] = 0.f;
    float4* sa = (float4*)(sA + f * kCp);
    sa[0] = *(float4*)&dx3[0];
    sa[1] = *(float4*)&dx3[4];
    sa[2] = *(float4*)&dx3[8];
  }
  __syncthreads();

  // ---- matmul3: out = dx3 @ W3 -> sB ----
  mm64(sA, W3, sB, cgi, fb);
  __syncthreads();

  // ---- residual epilogue ----
  if (T == 0) {
    // residual = emb[Z[atom]] in channel 0 only; store internal [f][12]
    float o[12];
    const float4* sb = (const float4*)(sB + f * kCp);
    *(float4*)&o[0] = sb[0];
    *(float4*)&o[4] = sb[1];
    *(float4*)&o[8] = sb[2];
    o[0] += emb[Z[atom] * kF + f];
    float4* xo = (float4*)(x_out + atom * kXs + f * kCp);
    xo[0] = *(float4*)&o[0];
    xo[1] = *(float4*)&o[4];
    xo[2] = *(float4*)&o[8];
  } else {
    float o[12];
    const float4* sb = (const float4*)(sB + f * kCp);
    const float4* xi = (const float4*)(x_in + atom * kXs + f * kCp);
    float4 a0 = sb[0], a1 = sb[1], a2 = sb[2];
    float4 b0 = xi[0], b1 = xi[1], b2 = xi[2];
    o[0] = a0.x + b0.x; o[1] = a0.y + b0.y; o[2] = a0.z + b0.z; o[3] = a0.w + b0.w;
    o[4] = a1.x + b1.x; o[5] = a1.y + b1.y; o[6] = a1.z + b1.z; o[7] = a1.w + b1.w;
    o[8] = a2.x + b2.x;
    // standard [c][f] layout: 9 coalesced b32 stores
    #pragma unroll
    for (int c = 0; c < 9; c++) {
      x_out[atom * (kNsh * kF) + c * kF + f] = o[c];
    }
  }
}

// ---------------------------------------------------------------------------
// Launch: 3 dispatches (kernel boundaries provide all coherence)
// ---------------------------------------------------------------------------
extern "C" void kernel_launch(void* const* d_in, const int* in_sizes, int n_in,
                              void* d_out, int out_size, void* d_ws, size_t ws_size,
                              hipStream_t stream) {
  const int* Z        = (const int*)d_in[0];
  const float* rij    = (const float*)d_in[1];
  const int* idx_i    = (const int*)d_in[2];
  const int* idx_j    = (const int*)d_in[3];
  const float* emb    = (const float*)d_in[4];
  const float* Wf     = (const float*)d_in[5];
  const float* bf     = (const float*)d_in[6];
  const float* W1     = (const float*)d_in[7];
  const float* W2     = (const float*)d_in[8];
  const float* W3     = (const float*)d_in[9];
  const float* Wg     = (const float*)d_in[10];
  const float* bg     = (const float*)d_in[11];
  float* out = (float*)d_out;

  float* x1    = (float*)d_ws;                       // 768,000
  float* Ypd   = x1 + kNAtoms * kXs;                 // 160,000
  float* Wpair = Ypd + kNPairs * 16;                 // 3,840,000
  int*   seg   = (int*)(Wpair + 2 * kNPairs * 192);  // 1001

  k_pre<<<kPreBlkTotal, 256, 0, stream>>>(rij, Wf, bf, idx_i, Ypd, Wpair, seg);

  // t = 0: emb-gather -> x1 (internal layout)
  k_inter<0><<<kNAtoms, 64, 0, stream>>>(
      Ypd, Wpair, seg, idx_j, Z, emb, x1,
      W1, W2, W3, Wg, bg, x1);

  // t = 1: x1-gather -> d_out (standard layout)
  k_inter<1><<<kNAtoms, 64, 0, stream>>>(
      Ypd, Wpair + kNPairs * 192, seg, idx_j, Z, emb, x1,
      W1 + kF * kF, W2 + kF * kF, W3 + kF * kF,
      Wg + kF * 192, bg + 192, out);
}

// Round 12
// 134.340 us; speedup vs baseline: 1.0546x; 1.0546x over previous
//
#include <hip/hip_runtime.h>
#include <cmath>

// ---------------------------------------------------------------------------
// Problem constants (from reference)
// ---------------------------------------------------------------------------
constexpr int kNsh    = 9;      // (LMAX+1)^2, LMAX=2
constexpr int kF      = 64;
constexpr int kNrbf   = 20;
constexpr int kNAtoms = 1000;
constexpr int kNPairs = 10000;
constexpr float kCutoffF = 5.0f;
constexpr int kMaxNZ  = 200;
constexpr int kCp     = 12;         // channel dim padded (9 -> 12) for b128
constexpr int kXs     = kF * kCp;   // 768 floats per atom, internal layout
constexpr int kNW     = 8;          // waves per atom-block

// ---------------------------------------------------------------------------
// Compile-time real Clebsch-Gordan table (mirrors the reference _real_cg)
// ---------------------------------------------------------------------------
struct CGSparse {
  int n;
  int c[kMaxNZ];
  int a[kMaxNZ];
  int b[kMaxNZ];
  float v[kMaxNZ];
};

constexpr double cfact(int n) {
  double r = 1.0;
  for (int i = 2; i <= n; i++) r *= (double)i;
  return r;
}
constexpr double cabs_(double x) { return x < 0 ? -x : x; }
constexpr double csqrt_(double x) {
  if (x <= 0.0) return 0.0;
  double g = x < 1.0 ? 1.0 : x;
  for (int i = 0; i < 60; i++) g = 0.5 * (g + x / g);
  return g;
}

constexpr double cg_cplx(int l1, int m1, int l2, int m2, int l3, int m3) {
  if (m3 != m1 + m2) return 0.0;
  int lo = l1 > l2 ? l1 - l2 : l2 - l1;
  if (l3 < lo || l3 > l1 + l2) return 0.0;
  double pre = csqrt_((2 * l3 + 1) * cfact(l3 + l1 - l2) * cfact(l3 - l1 + l2) *
                      cfact(l1 + l2 - l3) / cfact(l1 + l2 + l3 + 1));
  pre *= csqrt_(cfact(l3 + m3) * cfact(l3 - m3) * cfact(l1 - m1) *
                cfact(l1 + m1) * cfact(l2 - m2) * cfact(l2 + m2));
  double s = 0.0;
  for (int k = 0; k <= l1 + l2 - l3; k++) {
    int d0 = k, d1 = l1 + l2 - l3 - k, d2 = l1 - m1 - k;
    int d3 = l2 + m2 - k, d4 = l3 - l2 + m1 + k, d5 = l3 - l1 - m2 + k;
    if (d0 < 0 || d1 < 0 || d2 < 0 || d3 < 0 || d4 < 0 || d5 < 0) continue;
    double den = cfact(d0) * cfact(d1) * cfact(d2) * cfact(d3) * cfact(d4) * cfact(d5);
    s += ((k % 2) ? -1.0 : 1.0) / den;
  }
  return pre * s;
}

constexpr CGSparse build_cg() {
  CGSparse out{};
  int lidx[9] = {0, 1, 1, 1, 2, 2, 2, 2, 2};
  int midx[9] = {0, -1, 0, 1, -2, -1, 0, 1, 2};
  double Ur[9][9] = {};
  double Ui[9][9] = {};
  for (int l = 0; l <= 2; l++) {
    int base = l * l + l;
    Ur[base][base] = 1.0;
    for (int m = 1; m <= l; m++) {
      double s2 = 1.0 / csqrt_(2.0);
      double sgn = (m % 2) ? -1.0 : 1.0;
      Ur[base + m][base - m] = s2;
      Ur[base + m][base + m] = sgn * s2;
      Ui[base - m][base - m] = s2;
      Ui[base - m][base + m] = -sgn * s2;
    }
  }
  double cgr[9][9][9] = {};
  for (int i = 0; i < 9; i++)
    for (int j = 0; j < 9; j++)
      for (int k = 0; k < 9; k++) {
        double cv = cg_cplx(lidx[i], midx[i], lidx[j], midx[j], lidx[k], midx[k]);
        if (cv == 0.0) continue;
        for (int a2 = 0; a2 < 9; a2++) {
          if (Ur[a2][i] == 0.0 && Ui[a2][i] == 0.0) continue;
          for (int b2 = 0; b2 < 9; b2++) {
            if (Ur[b2][j] == 0.0 && Ui[b2][j] == 0.0) continue;
            for (int c2 = 0; c2 < 9; c2++) {
              if (Ur[c2][k] == 0.0 && Ui[c2][k] == 0.0) continue;
              double ar = Ur[a2][i], ai = Ui[a2][i];
              double br = Ur[b2][j], bi = Ui[b2][j];
              double cr = Ur[c2][k], ci = -Ui[c2][k];  // conj
              double pr = ar * br - ai * bi;
              double pi = ar * bi + ai * br;
              double rr = pr * cr - pi * ci;  // real part
              cgr[c2][a2][b2] += rr * cv;
            }
          }
        }
      }
  int n = 0;
  for (int c2 = 0; c2 < 9; c2++)
    for (int a2 = 0; a2 < 9; a2++)
      for (int b2 = 0; b2 < 9; b2++) {
        bool mask = ((lidx[a2] + lidx[b2]) % 2) == (lidx[c2] % 2);
        double v = mask ? cgr[c2][a2][b2] : 0.0;
        if (cabs_(v) > 1e-9) {
          out.c[n] = c2;
          out.a[n] = a2;
          out.b[n] = b2;
          out.v[n] = (float)v;
          n++;
        }
      }
  out.n = n;
  return out;
}

constexpr CGSparse CG = build_cg();
static_assert(CG.n > 0 && CG.n <= kMaxNZ, "CG table size out of range");

// ---------------------------------------------------------------------------
// k_pre: pair geometry + radial filters (both t) | segment offsets
// ---------------------------------------------------------------------------
constexpr int kPreBlkPairs = kNPairs / 4;                 // 2500
constexpr int kPreBlkSeg   = (kNAtoms + 1 + 255) / 256;   // 4
constexpr int kPreBlkTotal = kPreBlkPairs + kPreBlkSeg;

__global__ __launch_bounds__(256) void k_pre(
    const float* __restrict__ rij, const float* __restrict__ Wf,
    const float* __restrict__ bf, const int* __restrict__ idx_i,
    float* __restrict__ Ypd, float* __restrict__ Wpair,
    int* __restrict__ seg) {
  const int blk = blockIdx.x;
  if (blk < kPreBlkPairs) {
    int wv = threadIdx.x >> 6;
    int f = threadIdx.x & 63;
    int p = blk * 4 + wv;
    float rx = rij[3 * p + 0], ry = rij[3 * p + 1], rz = rij[3 * p + 2];
    float d = sqrtf(rx * rx + ry * ry + rz * rz);
    float inv = 1.0f / d;
    float x = rx * inv, y = ry * inv, z = rz * inv;
    const float c0 = 0.28209479177387814f;  // 0.5/sqrt(pi)
    const float c1 = 0.4886025119029199f;   // sqrt(3/(4pi))
    const float c2 = 1.0925484305920792f;   // 0.5*sqrt(15/pi)
    const float c3 = 0.31539156525252005f;  // 0.25*sqrt(5/pi)
    const float c4 = 0.5462742152960396f;   // 0.25*sqrt(15/pi)
    if (f < 9) {
      float yv =
          (f == 0) ? c0 :
          (f == 1) ? c1 * y :
          (f == 2) ? c1 * z :
          (f == 3) ? c1 * x :
          (f == 4) ? c2 * x * y :
          (f == 5) ? c2 * y * z :
          (f == 6) ? c3 * (3.0f * z * z - 1.0f) :
          (f == 7) ? c2 * x * z :
                     c4 * (x * x - y * y);
      Ypd[p * 16 + f] = yv;
    }
    float cut = (d < kCutoffF) ? 0.5f * (cosf(d * (float)(M_PI / 5.0)) + 1.0f) : 0.0f;
    float radial[kNrbf];
    const float width = kCutoffF / (kNrbf - 1);
    const float coef = -0.5f / (width * width);
    #pragma unroll
    for (int k = 0; k < kNrbf; k++) {
      float off = (kCutoffF * k) / (kNrbf - 1);
      float tt = d - off;
      radial[k] = expf(coef * tt * tt);
    }
    #pragma unroll
    for (int t = 0; t < 2; t++) {
      #pragma unroll
      for (int l = 0; l < 3; l++) {
        float w = bf[t * 192 + l * 64 + f];
        #pragma unroll
        for (int k = 0; k < kNrbf; k++) {
          w += radial[k] * Wf[t * (kNrbf * 192) + k * 192 + l * 64 + f];
        }
        Wpair[t * (kNPairs * 192) + p * 192 + l * 64 + f] = w * cut;
      }
    }
  } else {
    int a = (blk - kPreBlkPairs) * 256 + threadIdx.x;
    if (a <= kNAtoms) {
      int lo = 0, hi = kNPairs;
      while (lo < hi) {
        int mid = (lo + hi) >> 1;
        if (idx_i[mid] < a) lo = mid + 1; else hi = mid;
      }
      seg[a] = lo;
    }
  }
}

// ---------------------------------------------------------------------------
// Helpers
// ---------------------------------------------------------------------------
// k-split matmul partial: wave covers 8 k-slices of the 12c x 64f tile.
// W streamed from global (L2-broadcast) in two 4-slice register stages.
__device__ __forceinline__ void mm_phase(const float* __restrict__ sA,
                                         const float* __restrict__ W,
                                         float* __restrict__ sRw,
                                         int k0, int cgi, int fb) {
  if (cgi >= 3) return;
  const int c0 = cgi * 4;
  float acc[4][4];
  #pragma unroll
  for (int i = 0; i < 4; i++)
    #pragma unroll
    for (int j = 0; j < 4; j++) acc[i][j] = 0.f;
  #pragma unroll
  for (int half = 0; half < 2; half++) {
    float4 wr[4];
    #pragma unroll
    for (int kk = 0; kk < 4; kk++) {
      wr[kk] = *(const float4*)(W + (k0 + half * 4 + kk) * kF + fb);
    }
    #pragma unroll
    for (int kk = 0; kk < 4; kk++) {
      int k = k0 + half * 4 + kk;
      float4 av = *(const float4*)(sA + k * kCp + c0);
      float4 wv = wr[kk];
      float a[4] = {av.x, av.y, av.z, av.w};
      float w[4] = {wv.x, wv.y, wv.z, wv.w};
      #pragma unroll
      for (int i = 0; i < 4; i++)
        #pragma unroll
        for (int j = 0; j < 4; j++) acc[i][j] += a[i] * w[j];
    }
  }
  #pragma unroll
  for (int j = 0; j < 4; j++) {
    float4 v = {acc[0][j], acc[1][j], acc[2][j], acc[3][j]};
    *(float4*)(sRw + (fb + j) * kCp + c0) = v;
  }
}

// parallel reduce of kNW partials -> dst (192 float4s), threads 0..191
__device__ __forceinline__ void reduce_partials(const float (*sR)[kF * kCp],
                                                float* __restrict__ dst,
                                                int tid) {
  if (tid < 192) {
    float4 s = ((const float4*)sR[0])[tid];
    #pragma unroll
    for (int w = 1; w < kNW; w++) {
      float4 v = ((const float4*)sR[w])[tid];
      s.x += v.x; s.y += v.y; s.z += v.z; s.w += v.w;
    }
    ((float4*)dst)[tid] = s;
  }
}

// ---------------------------------------------------------------------------
// k_inter<T>: fused message + update, one block (8 waves, 512 thr) per atom.
// k-split by 8 (8 k-slices/wave) doubles waves/SIMD vs the 4-wave version.
// T==0: gather emb[Z[j]] (x0 virtual), write internal [f][12].
// T==1: gather x1, write standard [c][f] to out.
// ---------------------------------------------------------------------------
template <int T>
__global__ __launch_bounds__(512, 6) void k_inter(
    const float* __restrict__ Ypd, const float* __restrict__ Wpt,
    const int* __restrict__ seg, const int* __restrict__ idx_j,
    const int* __restrict__ Z, const float* __restrict__ emb,
    const float* __restrict__ x_in, const float* __restrict__ W1,
    const float* __restrict__ W2, const float* __restrict__ W3,
    const float* __restrict__ Wg, const float* __restrict__ bg,
    float* __restrict__ x_out) {
  const int atom = blockIdx.x;
  const int tid = threadIdx.x;
  const int wv = tid >> 6;          // wave 0..7
  const int lane = tid & 63;
  const int cgi = lane >> 4;        // 0..3 (3 idle in mm)
  const int fb = (lane & 15) * 4;
  const int k0 = wv * 8;            // k-range for this wave

  __shared__ __align__(16) float sA[kF * kCp];       // 3 KB  mm input, f-major
  __shared__ __align__(16) float sB[kF * kCp];       // 3 KB  reduced mm output
  __shared__ __align__(16) float sR[kNW][kF * kCp];  // 24 KB per-wave partials
  __shared__ __align__(16) float sGp[kNW][192];      // 6 KB  gate partials

  // ---- message + aggregation (pairs split across 8 waves) ----
  {
    float y[12];
    #pragma unroll
    for (int c = 0; c < 12; c++) y[c] = 0.f;
    const int s0 = seg[atom], s1 = seg[atom + 1];
    for (int p0 = s0 + wv; p0 < s1; p0 += kNW) {
      const int p = __builtin_amdgcn_readfirstlane(p0);
      const int j = __builtin_amdgcn_readfirstlane(idx_j[p]);
      const float* Wp = Wpt + p * 192;
      float Wl0 = Wp[lane], Wl1 = Wp[64 + lane], Wl2 = Wp[128 + lane];
      const float* Yp = Ypd + p * 16;
      float YW[9];
      YW[0] = Yp[0] * Wl0;
      YW[1] = Yp[1] * Wl1;
      YW[2] = Yp[2] * Wl1;
      YW[3] = Yp[3] * Wl1;
      #pragma unroll
      for (int b = 4; b < 9; b++) YW[b] = Yp[b] * Wl2;
      if (T == 0) {
        // x[j] = emb[Z[j]] in channel 0 only: CG folds to a==0 entries
        float e = emb[Z[j] * kF + lane];
        #pragma unroll
        for (int q = 0; q < CG.n; q++) {
          if (CG.a[q] == 0) y[CG.c[q]] += CG.v[q] * YW[CG.b[q]] * e;
        }
      } else {
        const float* xj = x_in + j * kXs + lane * kCp;
        float xv[12];
        *(float4*)&xv[0] = *(const float4*)(xj + 0);
        *(float4*)&xv[4] = *(const float4*)(xj + 4);
        *(float4*)&xv[8] = *(const float4*)(xj + 8);
        #pragma unroll
        for (int q = 0; q < CG.n; q++) {
          y[CG.c[q]] += CG.v[q] * YW[CG.b[q]] * xv[CG.a[q]];
        }
      }
    }
    float4* r4 = (float4*)(sR[wv] + lane * kCp);
    r4[0] = *(float4*)&y[0];
    r4[1] = *(float4*)&y[4];
    r4[2] = *(float4*)&y[8];
  }
  __syncthreads();  // B1
  reduce_partials(sR, sA, tid);   // sA = dx (f-major)
  __syncthreads();  // B2

  // ---- matmul1: ddx = dx @ W1 (k-split) ----
  mm_phase(sA, W1, sR[wv], k0, cgi, fb);
  __syncthreads();  // B3
  reduce_partials(sR, sB, tid);   // sB = ddx
  __syncthreads();  // B4

  // ---- tp: t2 = dx + CG(dx, ddx) (wave0; elementwise in f) -> sA ----
  if (wv == 0) {
    float dxv[12], ddx[12];
    {
      const float4* sa = (const float4*)(sA + lane * kCp);
      *(float4*)&dxv[0] = sa[0];
      *(float4*)&dxv[4] = sa[1];
      *(float4*)&dxv[8] = sa[2];
      const float4* sb = (const float4*)(sB + lane * kCp);
      *(float4*)&ddx[0] = sb[0];
      *(float4*)&ddx[4] = sb[1];
      *(float4*)&ddx[8] = sb[2];
    }
    float t2[12];
    #pragma unroll
    for (int c = 0; c < 9; c++) t2[c] = dxv[c];
    t2[9] = 0.f; t2[10] = 0.f; t2[11] = 0.f;
    #pragma unroll
    for (int q = 0; q < CG.n; q++) {
      t2[CG.c[q]] += CG.v[q] * dxv[CG.a[q]] * ddx[CG.b[q]];
    }
    float4* sa = (float4*)(sA + lane * kCp);
    sa[0] = *(float4*)&t2[0];
    sa[1] = *(float4*)&t2[4];
    sa[2] = *(float4*)&t2[8];
  }
  __syncthreads();  // B5

  // ---- matmul2: dx2 = t2 @ W2 (k-split) ----
  mm_phase(sA, W2, sR[wv], k0, cgi, fb);
  __syncthreads();  // B6
  reduce_partials(sR, sB, tid);   // sB = dx2
  __syncthreads();  // B7

  // ---- gate partials (k-split over 8 k) ----
  {
    float g0 = 0.f, g1 = 0.f, g2 = 0.f;
    #pragma unroll
    for (int kk = 0; kk < 8; kk++) {
      int k = k0 + kk;
      float a = sB[k * kCp];          // dx2[c=0][k], broadcast
      g0 += a * Wg[k * 192 + lane];
      g1 += a * Wg[k * 192 + 64 + lane];
      g2 += a * Wg[k * 192 + 128 + lane];
    }
    sGp[wv][lane] = g0;
    sGp[wv][64 + lane] = g1;
    sGp[wv][128 + lane] = g2;
  }
  __syncthreads();  // B8

  // ---- wave0: dx3 = dx2 * sigmoid(gate)[lidx] -> sA ----
  if (wv == 0) {
    float dx2v[12];
    {
      const float4* sb = (const float4*)(sB + lane * kCp);
      *(float4*)&dx2v[0] = sb[0];
      *(float4*)&dx2v[4] = sb[1];
      *(float4*)&dx2v[8] = sb[2];
    }
    float g0 = bg[lane], g1 = bg[64 + lane], g2 = bg[128 + lane];
    #pragma unroll
    for (int w = 0; w < kNW; w++) {
      g0 += sGp[w][lane];
      g1 += sGp[w][64 + lane];
      g2 += sGp[w][128 + lane];
    }
    g0 = 1.f / (1.f + expf(-g0));
    g1 = 1.f / (1.f + expf(-g1));
    g2 = 1.f / (1.f + expf(-g2));
    float dx3[12];
    dx3[0] = dx2v[0] * g0;
    dx3[1] = dx2v[1] * g1;
    dx3[2] = dx2v[2] * g1;
    dx3[3] = dx2v[3] * g1;
    #pragma unroll
    for (int c = 4; c < 9; c++) dx3[c] = dx2v[c] * g2;
    dx3[9] = 0.f; dx3[10] = 0.f; dx3[11] = 0.f;
    float4* sa = (float4*)(sA + lane * kCp);
    sa[0] = *(float4*)&dx3[0];
    sa[1] = *(float4*)&dx3[4];
    sa[2] = *(float4*)&dx3[8];
  }
  __syncthreads();  // B9

  // ---- matmul3: out = dx3 @ W3 (k-split) ----
  mm_phase(sA, W3, sR[wv], k0, cgi, fb);
  __syncthreads();  // B10

  // ---- residual output ----
  if (T == 0) {
    // residual = x0 = emb[Z[atom]] in channel 0 only; out internal [f][12]
    if (tid < 192) {
      const int f = tid / 3, r = tid % 3;
      float4 s = ((const float4*)sR[0])[tid];
      #pragma unroll
      for (int w = 1; w < kNW; w++) {
        float4 v = ((const float4*)sR[w])[tid];
        s.x += v.x; s.y += v.y; s.z += v.z; s.w += v.w;
      }
      if (r == 0) s.x += emb[Z[atom] * kF + f];
      *(float4*)(x_out + atom * kXs + tid * 4) = s;
    }
  } else {
    // sum + residual (f-major, b128) -> sA, then c-major store
    if (tid < 192) {
      float4 s = ((const float4*)sR[0])[tid];
      #pragma unroll
      for (int w = 1; w < kNW; w++) {
        float4 v = ((const float4*)sR[w])[tid];
        s.x += v.x; s.y += v.y; s.z += v.z; s.w += v.w;
      }
      float4 xi = *(const float4*)(x_in + atom * kXs + tid * 4);
      s.x += xi.x; s.y += xi.y; s.z += xi.z; s.w += xi.w;
      ((float4*)sA)[tid] = s;
    }
    __syncthreads();  // B11
    #pragma unroll
    for (int r = 0; r < 2; r++) {
      int i = r * 512 + tid;        // 0..1023, only < 576 valid
      if (i < kNsh * kF) {
        int c = i >> 6, f = i & 63;
        x_out[atom * (kNsh * kF) + i] = sA[f * kCp + c];
      }
    }
  }
}

// ---------------------------------------------------------------------------
// Launch: 3 dispatches (kernel boundaries provide all coherence)
// ---------------------------------------------------------------------------
extern "C" void kernel_launch(void* const* d_in, const int* in_sizes, int n_in,
                              void* d_out, int out_size, void* d_ws, size_t ws_size,
                              hipStream_t stream) {
  const int* Z        = (const int*)d_in[0];
  const float* rij    = (const float*)d_in[1];
  const int* idx_i    = (const int*)d_in[2];
  const int* idx_j    = (const int*)d_in[3];
  const float* emb    = (const float*)d_in[4];
  const float* Wf     = (const float*)d_in[5];
  const float* bf     = (const float*)d_in[6];
  const float* W1     = (const float*)d_in[7];
  const float* W2     = (const float*)d_in[8];
  const float* W3     = (const float*)d_in[9];
  const float* Wg     = (const float*)d_in[10];
  const float* bg     = (const float*)d_in[11];
  float* out = (float*)d_out;

  float* x1    = (float*)d_ws;                       // 768,000
  float* Ypd   = x1 + kNAtoms * kXs;                 // 160,000
  float* Wpair = Ypd + kNPairs * 16;                 // 3,840,000
  int*   seg   = (int*)(Wpair + 2 * kNPairs * 192);  // 1001

  k_pre<<<kPreBlkTotal, 256, 0, stream>>>(rij, Wf, bf, idx_i, Ypd, Wpair, seg);

  // t = 0: emb-gather -> x1 (internal layout)
  k_inter<0><<<kNAtoms, 512, 0, stream>>>(
      Ypd, Wpair, seg, idx_j, Z, emb, x1,
      W1, W2, W3, Wg, bg, x1);

  // t = 1: x1-gather -> d_out (standard layout)
  k_inter<1><<<kNAtoms, 512, 0, stream>>>(
      Ypd, Wpair + kNPairs * 192, seg, idx_j, Z, emb, x1,
      W1 + kF * kF, W2 + kF * kF, W3 + kF * kF,
      Wg + kF * 192, bg + 192, out);
}